// Round 1
// 96.911 us; speedup vs baseline: 1.0225x; 1.0225x over previous
//
#include <hip/hip_runtime.h>

// SpMM: out[r, :] = sum_{e: row[e]==r} vals[e] * embeds[col[e], :]
// N_NODES=50000, N_EDGES=800000, D=64. row_idx is SORTED.
//
// R11: the 99us is ~90us harness workspace-repoison fills (44.5us x2, seen in
// rocprof) + ~10us of our kernels. Of ours, spmm is VALU-ISSUE bound: int8
// dequant = 3 VALU/MAC (bfe+cvt+fmac) + scales gather. Switch table to bf16:
//   - no scales (w = vals[e] directly): kills the scales gather + prep reduce
//   - unpack = shift/and (1 VALU/feat), pairs feed v_pk_fma_f32 (2 FMA/instr)
//     -> ~1.5 VALU/MAC vs 3
//   - 8 edge slots (g=lane>>3) x 8 lanes (h=lane&7, 16B = 8 feats): 4 k-groups
//     of 8 edges per iter, wave-uniform skip of empty groups (Poisson(16) ->
//     avg 2.5/4 groups run). Butterfly 7 shfl (vs 15).
//   - every row written (deg-0 rows store 0) -> no output memset.
// accuracy: bf16 RNE (~0.4% rel) beats int8 per-row (absmax was 0.088 / 0.29).

constexpr int N_NODES = 50000;
constexpr int N_EDGES = 800000;
constexpr int D_FEAT  = 64;

using uvec4 = __attribute__((ext_vector_type(4))) unsigned int;
using fvec4 = __attribute__((ext_vector_type(4))) float;
using f32x2 = __attribute__((ext_vector_type(2))) float;

// d_ws layout
constexpr size_t WS_ROWPTR_OFF = 0;          // (N_NODES+1) ints (~200 KB)
constexpr size_t WS_TBL_OFF    = 1u << 20;   // 50000*64 bf16 = 6.4 MB

constexpr int ROWPTR_BLOCKS = (N_EDGES + 255) / 256;        // 3125
constexpr int CONV_THREADS  = N_NODES * D_FEAT / 8;         // 400000 (8 feat/thread)
constexpr int CONV_BLOCKS   = (CONV_THREADS + 255) / 256;   // 1563

__device__ inline unsigned pack_bf16x2(float a, float b) {
    // RNE truncate f32->bf16; lo = a, hi = b.
    unsigned ua = __float_as_uint(a), ub = __float_as_uint(b);
    ua = (ua + 0x7fffu + ((ua >> 16) & 1u)) >> 16;
    ub = (ub + 0x7fffu + ((ub >> 16) & 1u)) & 0xffff0000u;
    return ua | ub;
}

__global__ __launch_bounds__(256) void prep_kernel(
    const int*      __restrict__ row_idx,
    const float*    __restrict__ embeds,
    int*            __restrict__ row_ptr,
    unsigned short* __restrict__ tbl)
{
    if (blockIdx.x < ROWPTR_BLOCKS) {
        const int e = blockIdx.x * 256 + threadIdx.x;
        if (e >= N_EDGES) return;
        const int r     = row_idx[e];
        const int rprev = (e == 0) ? -1 : row_idx[e - 1];
        for (int q = rprev + 1; q <= r; ++q) row_ptr[q] = e;   // fills empty rows
        if (e == N_EDGES - 1) {
            for (int q = r + 1; q <= N_NODES; ++q) row_ptr[q] = N_EDGES;
        }
    } else {
        // f32 -> bf16 table convert: 8 features per thread (32B read, 16B write).
        const int t = (blockIdx.x - ROWPTR_BLOCKS) * 256 + threadIdx.x;
        if (t >= CONV_THREADS) return;
        const fvec4* __restrict__ src = (const fvec4*)embeds;
        const fvec4 x0 = src[t * 2];
        const fvec4 x1 = src[t * 2 + 1];
        uvec4 p;
        p[0] = pack_bf16x2(x0[0], x0[1]);
        p[1] = pack_bf16x2(x0[2], x0[3]);
        p[2] = pack_bf16x2(x1[0], x1[1]);
        p[3] = pack_bf16x2(x1[2], x1[3]);
        ((uvec4*)tbl)[t] = p;
    }
}

__global__ __launch_bounds__(256) void gcn_spmm_kernel(
    const int*            __restrict__ row_ptr,
    const int*            __restrict__ col_idx,
    const float*          __restrict__ vals,
    const unsigned short* __restrict__ tbl,
    float*                __restrict__ out)
{
    const int row = blockIdx.x * 4 + (threadIdx.x >> 6);  // one wave per row
    if (row >= N_NODES) return;

    const int lane = threadIdx.x & 63;
    const int g    = lane >> 3;          // edge slot (8 per k-group)
    const int h    = lane & 7;           // 16B chunk: features [h*8, h*8+8)

    const int es = __builtin_amdgcn_readfirstlane(row_ptr[row]);
    const int ee = __builtin_amdgcn_readfirstlane(row_ptr[row + 1]);

    const uvec4* __restrict__ tbl16 = (const uvec4*)tbl;   // 8 uvec4 per row

    f32x2 acc[4];
#pragma unroll
    for (int i = 0; i < 4; ++i) { acc[i][0] = 0.f; acc[i][1] = 0.f; }

    for (int base = es; base < ee; base += 32) {
#pragma unroll
        for (int k = 0; k < 4; ++k) {
            // wave-uniform skip of empty 8-edge groups (deg avg 16 -> ~2.5/4 run)
            if (base + k * 8 < ee) {
                const int e = base + k * 8 + g;
                const int i = (e < ee) ? e : ee - 1;       // clamp (in-bounds)
                const int c = col_idx[i];
                const float v = (e < ee) ? vals[i] : 0.f;
                // 8-edge gather: 8 lanes x 16B = one 128B bf16 row per slot.
                const uvec4 q = tbl16[c * 8 + h];
                f32x2 w; w[0] = v; w[1] = v;
#pragma unroll
                for (int d = 0; d < 4; ++d) {
                    f32x2 f;
                    f[0] = __uint_as_float(q[d] << 16);           // feat h*8+2d
                    f[1] = __uint_as_float(q[d] & 0xffff0000u);   // feat h*8+2d+1
                    asm("v_pk_fma_f32 %0, %1, %2, %0"
                        : "+v"(acc[d]) : "v"(w), "v"(f));
                }
            }
        }
    }

    // Reduce-scatter butterfly over the 8 edge slots (lane bits 3..5).
    // After stage k the live-value count halves; lane ends with the single
    // feature j == g.
    float a[8];
#pragma unroll
    for (int d = 0; d < 4; ++d) { a[2 * d] = acc[d][0]; a[2 * d + 1] = acc[d][1]; }

    float a4[4];
    {
        const int b = g & 1;
#pragma unroll
        for (int j = 0; j < 4; ++j) {
            const float send = b ? a[2 * j] : a[2 * j + 1];
            const float keep = b ? a[2 * j + 1] : a[2 * j];
            a4[j] = keep + __shfl_xor(send, 8);
        }
    }
    float a2[2];
    {
        const int b = (g >> 1) & 1;
#pragma unroll
        for (int j = 0; j < 2; ++j) {
            const float send = b ? a4[2 * j] : a4[2 * j + 1];
            const float keep = b ? a4[2 * j + 1] : a4[2 * j];
            a2[j] = keep + __shfl_xor(send, 16);
        }
    }
    float a1;
    {
        const int b = (g >> 2) & 1;
        const float send = b ? a2[0] : a2[1];
        const float keep = b ? a2[1] : a2[0];
        a1 = keep + __shfl_xor(send, 32);
    }

    // Lane (g,h) owns feature h*8+g; all 64 lanes hit one 256B span.
    __builtin_nontemporal_store(a1, out + row * D_FEAT + h * 8 + g);
}

extern "C" void kernel_launch(void* const* d_in, const int* in_sizes, int n_in,
                              void* d_out, int out_size, void* d_ws, size_t ws_size,
                              hipStream_t stream) {
    const int*   row_idx = (const int*)  d_in[0];
    const int*   col_idx = (const int*)  d_in[1];
    const float* vals    = (const float*)d_in[2];
    const float* embeds  = (const float*)d_in[3];
    float*       out     = (float*)      d_out;

    char* ws = (char*)d_ws;
    int*            row_ptr = (int*)           (ws + WS_ROWPTR_OFF);
    unsigned short* tbl     = (unsigned short*)(ws + WS_TBL_OFF);

    prep_kernel<<<ROWPTR_BLOCKS + CONV_BLOCKS, 256, 0, stream>>>(
        row_idx, embeds, row_ptr, tbl);

    // One wave per row, 4 rows per block.
    gcn_spmm_kernel<<<(N_NODES + 3) / 4, 256, 0, stream>>>(
        row_ptr, col_idx, vals, tbl, out);
}